// Round 10
// baseline (207.533 us; speedup 1.0000x reference)
//
#include <hip/hip_runtime.h>
#include <stdint.h>

#define DIMD 512
#define BATCH 512
#define KSAMP 10
#define NCLS 8192
#define TREJ 32

typedef __bf16 bf16x8 __attribute__((ext_vector_type(8)));
typedef float f32x4 __attribute__((ext_vector_type(4)));

// ---------------- RNG (counter-based, deterministic) ----------------
__device__ inline uint64_t sm64(uint64_t x) {
  x += 0x9E3779B97F4A7C15ull;
  x = (x ^ (x >> 30)) * 0xBF58476D1CE4E5B9ull;
  x = (x ^ (x >> 27)) * 0x94D049BB133111EBull;
  return x ^ (x >> 31);
}
__device__ inline float u01(uint32_t u) {
  return ((float)u + 0.5f) * 2.3283064365386963e-10f;
}
__device__ inline float normal_from(uint64_t r) {
  float u1 = u01((uint32_t)(r >> 32));
  float u2 = u01((uint32_t)r);
  return sqrtf(-2.0f * __logf(u1)) * __cosf(6.28318530718f * u2);
}
__device__ inline float gamma255(uint64_t& ctr) {
  const float dg = 255.1666667f;
  const float cg = 0.02086730f;
  for (int i = 0; i < 16; i++) {
    uint64_t r = sm64(ctr++);
    float x = normal_from(r);
    float t = fmaf(cg, x, 1.0f);
    if (t <= 0.0f) continue;
    float v3 = t * t * t;
    uint64_t r2 = sm64(ctr++);
    float u3 = u01((uint32_t)(r2 >> 32));
    if (__logf(u3) < 0.5f * x * x + dg * (1.0f - v3 + __logf(v3))) return dg * v3;
  }
  return dg;
}
__device__ inline float wave_sum(float v) {
  #pragma unroll
  for (int o = 32; o > 0; o >>= 1) v += __shfl_down(v, o, 64);
  return __shfl(v, 0, 64);
}
__device__ inline float vmf_logc(float k) {
  float k2 = k * k;
  float sm = sqrtf(65280.25f + k2);
  float sp = sqrtf(65792.25f + k2);
  return 127.75f * (logf(255.5f + sm) + logf(255.5f + sp)) - 0.5f * (sm + sp);
}
__device__ inline unsigned short f2bf(float f) {
  uint32_t u = __float_as_uint(f);
  uint32_t r = (u + 0x7FFFu + ((u >> 16) & 1u)) >> 16;
  return (unsigned short)r;
}
__device__ inline float bf2f(unsigned short s) {
  return __uint_as_float(((uint32_t)s) << 16);
}
// lgkm-only barrier: buffer_loads (wave-private VGPR dests) stay in flight.
__device__ inline void sync_lds() {
  asm volatile("s_waitcnt lgkmcnt(0)\n\ts_barrier" ::: "memory");
}

// ---------- fused prep (blocks 0..2047, one WAVE per class) + sample ----------
__global__ __launch_bounds__(256) void prep_sample(const float* __restrict__ weight,
                                                   const float* __restrict__ params,
                                                   const float* __restrict__ lscale,
                                                   unsigned short* __restrict__ muWb,
                                                   float4* __restrict__ cparams,
                                                   float* __restrict__ rowsum,
                                                   float4* __restrict__ out4,
                                                   unsigned short* __restrict__ Sb) {
  int blk = blockIdx.x, tid = threadIdx.x;
  int wave = tid >> 6, lane = tid & 63;
  if (blk < 2048) {
    out4[(size_t)blk * 512 + tid]       = make_float4(0.f, 0.f, 0.f, 0.f);
    out4[(size_t)blk * 512 + 256 + tid] = make_float4(0.f, 0.f, 0.f, 0.f);
    if (blk < 20) rowsum[blk * 256 + tid] = 0.0f;   // 20*256 = 5120

    int c = blk * 4 + wave;                 // one wave per class, no barriers
    const float* wr = weight + (size_t)c * (DIMD + 2) + 1;
    float v[8];
    float n2 = 0.0f;
    #pragma unroll
    for (int j = 0; j < 8; j++) { v[j] = wr[j * 64 + lane]; n2 += v[j] * v[j]; }
    n2 = wave_sum(n2);
    float inv = rsqrtf(n2);
    #pragma unroll
    for (int j = 0; j < 8; j++)
      muWb[(size_t)c * DIMD + j * 64 + lane] = f2bf(v[j] * inv);

    float hik = wr[DIMD];                   // col 513
    float kw = expf(-hik);
    float k1 = expf(lscale[0]);
    float lcw = vmf_logc(kw);
    float A2 = fmaf(k1, k1, kw * kw);
    float B2 = 2.0f * k1 * kw;
    const float X0 = 0.9238795f, X1 = 0.3826834f;
    int l3 = lane & 3;
    float Xj = (l3 == 0) ? X0 : (l3 == 1) ? X1 : (l3 == 2) ? -X1 : -X0;
    float gj = lcw - vmf_logc(sqrtf(fmaf(B2, Xj, A2)));
    float g0 = __shfl(gj, 0, 64), g1 = __shfl(gj, 1, 64);
    float g2 = __shfl(gj, 2, 64), g3 = __shfl(gj, 3, 64);
    if (lane == 0) {
      float b0 = 0.25f * (g0 + g1 + g2 + g3);
      float b1 = 0.5f * (X0 * (g0 - g3) + X1 * (g1 - g2));
      float b2 = 0.5f * 0.7071068f * ((g0 + g3) - (g1 + g2));
      float b3 = 0.5f * (X1 * (g0 - g3) - X0 * (g1 - g2));
      const float L2E = 1.4426950409f;
      cparams[c] = make_float4((b0 - b2) * L2E, (b1 - 3.0f * b3) * L2E,
                               (2.0f * b2) * L2E, (4.0f * b3) * L2E);
    }
  } else {
    int row = (blk - 2048) * 4 + wave;      // b*KSAMP + k
    int b = row / KSAMP;
    const float* pr = params + (size_t)b * (DIMD + 2) + 1;

    float mu[8];
    float n2 = 0.0f;
    #pragma unroll
    for (int j = 0; j < 8; j++) { mu[j] = pr[j * 64 + lane]; n2 += mu[j] * mu[j]; }
    n2 = wave_sum(n2);
    float invn = rsqrtf(n2);
    #pragma unroll
    for (int j = 0; j < 8; j++) mu[j] *= invn;

    float kap = __expf(-pr[DIMD]);
    float bb = (-2.0f * kap + sqrtf(fmaf(4.0f * kap, kap, 511.0f * 511.0f))) / 511.0f;
    float x0 = (1.0f - bb) / (1.0f + bb);
    float cc = kap * x0 + 511.0f * __logf(1.0f - x0 * x0);

    uint64_t ctr = (((uint64_t)(row + 1)) << 32) | ((uint64_t)lane << 8);
    float g1 = gamma255(ctr);
    float g2 = gamma255(ctr);
    float z = g1 / (g1 + g2);
    float wt = (1.0f - (1.0f + bb) * z) / (1.0f - (1.0f - bb) * z);
    uint64_t r = sm64(ctr++);
    float u = u01((uint32_t)(r >> 32));
    float lhs = kap * wt + 511.0f * __logf(1.0f - x0 * wt) - cc;
    bool acc = (lane < TREJ) && (lhs >= __logf(fmaxf(u, 1e-10f)));
    uint64_t mask = __ballot(acc);
    int sel = mask ? (__ffsll((unsigned long long)mask) - 1) : 0;
    float w = __shfl(wt, sel, 64);

    uint64_t cbase = (((uint64_t)(row + 1)) << 32) | 0x40000000ull;
    float v[8];
    #pragma unroll
    for (int j = 0; j < 8; j++) v[j] = normal_from(sm64(cbase + (uint64_t)(j * 64 + lane)));
    float d = 0.0f;
    #pragma unroll
    for (int j = 0; j < 8; j++) d += v[j] * mu[j];
    d = wave_sum(d);
    float t2 = 0.0f;
    #pragma unroll
    for (int j = 0; j < 8; j++) { v[j] -= d * mu[j]; t2 += v[j] * v[j]; }
    t2 = wave_sum(t2);
    float ivt = rsqrtf(t2);
    float st = sqrtf(fmaxf(0.0f, 1.0f - w * w)) * ivt;
    float sv[8];
    float s2 = 0.0f;
    #pragma unroll
    for (int j = 0; j < 8; j++) { sv[j] = fmaf(st, v[j], w * mu[j]); s2 += sv[j] * sv[j]; }
    s2 = wave_sum(s2);
    float is = rsqrtf(s2);
    #pragma unroll
    for (int j = 0; j < 8; j++) Sb[(size_t)row * DIMD + j * 64 + lane] = f2bf(sv[j] * is);
  }
}

// MFMA GEMM (bf16, 256x128 tile, BK=32). R8's tile geometry (wave-tile
// 64x128 -> 42.7 FLOP per LDS byte) + R9's verified AITER loop: fully
// unrolled K-loop, register prefetch depth 2 (static indices only),
// ds_write with the verified kg/slot swizzle, lgkm-only barriers so
// buffer_loads stay in flight across them.
__global__ __launch_bounds__(256, 2) void gemm_lse(const unsigned short* __restrict__ Sb,
                                                   const unsigned short* __restrict__ Wb,
                                                   const float4* __restrict__ cparams,
                                                   float* __restrict__ rowsum) {
  __shared__ __align__(16) unsigned short As[2][256 * 32];   // 2 x 16 KB
  __shared__ __align__(16) unsigned short Bs[2][128 * 32];   // 2 x 8 KB
  int tid = threadIdx.x;
  int lane = tid & 63, wave = tid >> 6;
  int tx = lane & 15, tz = lane >> 4;

  int id = blockIdx.x;                       // 64 col-tiles x 20 row-tiles = 1280
  int xcd = id & 7, lid = id >> 3;           // 160 blocks per XCD
  int c0 = (xcd * 8 + (lid & 7)) * 128;      // 8-coltile stripe per XCD (1 MB W in L2)
  int r0 = (lid >> 3) * 256;                 // sweep 20 row tiles

  int kg = (lane & 3) ^ ((lane >> 3) & 3);   // verified swizzle
  int slot = lane & 3;
  int srowA = wave * 64 + (lane >> 2);       // A: 64 rows/wave, chunks +0/16/32/48
  int srowB = wave * 32 + (lane >> 2);       // B: 32 rows/wave, chunks +0/16
  const unsigned short* gA = Sb + (size_t)(r0 + srowA) * DIMD + kg * 8;
  const unsigned short* gB = Wb + (size_t)(c0 + srowB) * DIMD + kg * 8;
  int ldsA = srowA * 32 + slot * 8;
  int ldsB = srowB * 32 + slot * 8;

  f32x4 acc[4][8];
  #pragma unroll
  for (int i = 0; i < 4; i++)
    #pragma unroll
    for (int j = 0; j < 8; j++) acc[i][j] = (f32x4){0.f, 0.f, 0.f, 0.f};

  int4 ar0[4], br0[2];   // set 0: even chunks
  int4 ar1[4], br1[2];   // set 1: odd chunks

#define LOADCH(CI, AR, BR)                                   \
  { AR[0] = *(const int4*)(gA + (CI) * 32);                  \
    AR[1] = *(const int4*)(gA + 16 * DIMD + (CI) * 32);      \
    AR[2] = *(const int4*)(gA + 32 * DIMD + (CI) * 32);      \
    AR[3] = *(const int4*)(gA + 48 * DIMD + (CI) * 32);      \
    BR[0] = *(const int4*)(gB + (CI) * 32);                  \
    BR[1] = *(const int4*)(gB + 16 * DIMD + (CI) * 32); }

#define WRITELDS(P, AR, BR)                                  \
  { *(int4*)&As[P][ldsA]            = AR[0];                 \
    *(int4*)&As[P][ldsA + 16 * 32]  = AR[1];                 \
    *(int4*)&As[P][ldsA + 32 * 32]  = AR[2];                 \
    *(int4*)&As[P][ldsA + 48 * 32]  = AR[3];                 \
    *(int4*)&Bs[P][ldsB]            = BR[0];                 \
    *(int4*)&Bs[P][ldsB + 16 * 32]  = BR[1]; }

#define COMPUTE(P)                                           \
  { bf16x8 af[4], bf[8];                                     \
    int sA_ = tz ^ ((tx >> 1) & 3);                          \
    _Pragma("unroll")                                        \
    for (int mi = 0; mi < 4; mi++)                           \
      af[mi] = *(const bf16x8*)&As[P][(wave * 64 + mi * 16 + tx) * 32 + sA_ * 8]; \
    _Pragma("unroll")                                        \
    for (int ni = 0; ni < 8; ni++)                           \
      bf[ni] = *(const bf16x8*)&Bs[P][(ni * 16 + tx) * 32 + sA_ * 8]; \
    _Pragma("unroll")                                        \
    for (int mi = 0; mi < 4; mi++)                           \
      _Pragma("unroll")                                      \
      for (int ni = 0; ni < 8; ni++)                         \
        acc[mi][ni] = __builtin_amdgcn_mfma_f32_16x16x32_bf16(af[mi], bf[ni], acc[mi][ni], 0, 0, 0); }

  // prologue: chunks 0,1 in flight; publish chunk 0
  LOADCH(0, ar0, br0);
  LOADCH(1, ar1, br1);
  WRITELDS(0, ar0, br0);
  sync_lds();

#define GITER_EVEN(IT)                                       \
  { if ((IT) + 2 < 16) LOADCH((IT) + 2, ar0, br0);           \
    COMPUTE(0);                                              \
    if ((IT) + 1 < 16) WRITELDS(1, ar1, br1);                \
    if ((IT) < 15) sync_lds(); }

#define GITER_ODD(IT)                                        \
  { if ((IT) + 2 < 16) LOADCH((IT) + 2, ar1, br1);           \
    COMPUTE(1);                                              \
    if ((IT) + 1 < 16) WRITELDS(0, ar0, br0);                \
    if ((IT) < 15) sync_lds(); }

  GITER_EVEN(0)  GITER_ODD(1)  GITER_EVEN(2)  GITER_ODD(3)
  GITER_EVEN(4)  GITER_ODD(5)  GITER_EVEN(6)  GITER_ODD(7)
  GITER_EVEN(8)  GITER_ODD(9)  GITER_EVEN(10) GITER_ODD(11)
  GITER_EVEN(12) GITER_ODD(13) GITER_EVEN(14) GITER_ODD(15)

  // epilogue: s += 2^(cubic(cos)) per class (R8's verified 256-tile map)
  float4 cp[8];
  #pragma unroll
  for (int ni = 0; ni < 8; ni++) cp[ni] = cparams[c0 + ni * 16 + tx];

  #pragma unroll
  for (int mi = 0; mi < 4; mi++) {
    #pragma unroll
    for (int reg = 0; reg < 4; reg++) {
      float s = 0.0f;
      #pragma unroll
      for (int ni = 0; ni < 8; ni++) {
        float cv = acc[mi][ni][reg];
        float g = fmaf(fmaf(fmaf(cp[ni].w, cv, cp[ni].z), cv, cp[ni].y), cv, cp[ni].x);
        s += exp2f(g);
      }
      #pragma unroll
      for (int o = 1; o < 16; o <<= 1) s += __shfl_xor(s, o, 64);
      if (tx == 0)
        atomicAdd(&rowsum[r0 + wave * 64 + mi * 16 + tz * 4 + reg], s);
    }
  }
}

// finalize: renormalizes mu_x from params directly
__global__ __launch_bounds__(64) void finalize_kernel(const float* __restrict__ params,
                                                      const unsigned short* __restrict__ muWb,
                                                      const float* __restrict__ rowsum,
                                                      const int* __restrict__ labels,
                                                      const float* __restrict__ lscale,
                                                      float* __restrict__ out) {
  int b = blockIdx.x;
  int lane = threadIdx.x;
  int lab = labels[b];
  const float* pr = params + (size_t)b * (DIMD + 2) + 1;
  float xv[8];
  float n2 = 0.0f;
  #pragma unroll
  for (int j = 0; j < 8; j++) { xv[j] = pr[j * 64 + lane]; n2 += xv[j] * xv[j]; }
  n2 = wave_sum(n2);
  float invn = rsqrtf(n2);
  float d = 0.0f;
  #pragma unroll
  for (int j = 0; j < 8; j++)
    d += xv[j] * invn * bf2f(muWb[(size_t)lab * DIMD + j * 64 + lane]);
  d = wave_sum(d);
  if (lane == 0) {
    float k1 = expf(lscale[0]);
    float acc = 0.0f;
    #pragma unroll
    for (int k = 0; k < KSAMP; k++) acc += __logf(rowsum[b * KSAMP + k]);
    float loss = acc * (1.0f / KSAMP) - k1 * d;
    out[(size_t)b * NCLS + lab] = -loss;
  }
}

// ---------------- launch ----------------
extern "C" void kernel_launch(void* const* d_in, const int* in_sizes, int n_in,
                              void* d_out, int out_size, void* d_ws, size_t ws_size,
                              hipStream_t stream) {
  const float* params = (const float*)d_in[0];
  const float* weight = (const float*)d_in[1];
  const float* lscale = (const float*)d_in[2];
  const int*   labels = (const int*)d_in[3];
  float* out = (float*)d_out;
  char* ws = (char*)d_ws;

  unsigned short* muWb   = (unsigned short*)(ws);                   // 8192*512*2  = 8,388,608
  unsigned short* Sb     = (unsigned short*)(ws + 8388608);         // 5120*512*2  = 5,242,880
  float4*         cparams= (float4*)(ws + 13631488);                // 8192*16     =   131,072
  float*          rowsum = (float*)(ws + 13762560);                 // 5120*4      =    20,480

  hipLaunchKernelGGL(prep_sample, dim3(2048 + BATCH * KSAMP / 4), dim3(256), 0, stream,
                     weight, params, lscale, muWb, cparams, rowsum, (float4*)out, Sb);
  hipLaunchKernelGGL(gemm_lse, dim3((NCLS / 128) * (BATCH * KSAMP / 256)), dim3(256), 0, stream,
                     Sb, muWb, cparams, rowsum);
  hipLaunchKernelGGL(finalize_kernel, dim3(BATCH), dim3(64), 0, stream,
                     params, muWb, rowsum, labels, lscale, out);
}

// Round 11
// 141.034 us; speedup vs baseline: 1.4715x; 1.4715x over previous
//
#include <hip/hip_runtime.h>
#include <stdint.h>

#define DIMD 512
#define BATCH 512
#define KSAMP 10
#define NCLS 8192
#define TREJ 32

typedef float f32x4 __attribute__((ext_vector_type(4)));
typedef long l2 __attribute__((ext_vector_type(2)));

// ---------------- RNG (counter-based, deterministic) ----------------
__device__ inline uint64_t sm64(uint64_t x) {
  x += 0x9E3779B97F4A7C15ull;
  x = (x ^ (x >> 30)) * 0xBF58476D1CE4E5B9ull;
  x = (x ^ (x >> 27)) * 0x94D049BB133111EBull;
  return x ^ (x >> 31);
}
__device__ inline float u01(uint32_t u) {
  return ((float)u + 0.5f) * 2.3283064365386963e-10f;
}
__device__ inline float normal_from(uint64_t r) {
  float u1 = u01((uint32_t)(r >> 32));
  float u2 = u01((uint32_t)r);
  return sqrtf(-2.0f * __logf(u1)) * __cosf(6.28318530718f * u2);
}
__device__ inline float gamma255(uint64_t& ctr) {
  const float dg = 255.1666667f;
  const float cg = 0.02086730f;
  for (int i = 0; i < 16; i++) {
    uint64_t r = sm64(ctr++);
    float x = normal_from(r);
    float t = fmaf(cg, x, 1.0f);
    if (t <= 0.0f) continue;
    float v3 = t * t * t;
    uint64_t r2 = sm64(ctr++);
    float u3 = u01((uint32_t)(r2 >> 32));
    if (__logf(u3) < 0.5f * x * x + dg * (1.0f - v3 + __logf(v3))) return dg * v3;
  }
  return dg;
}
__device__ inline float wave_sum(float v) {
  #pragma unroll
  for (int o = 32; o > 0; o >>= 1) v += __shfl_down(v, o, 64);
  return __shfl(v, 0, 64);
}
__device__ inline float vmf_logc(float k) {
  float k2 = k * k;
  float sm = sqrtf(65280.25f + k2);
  float sp = sqrtf(65792.25f + k2);
  return 127.75f * (logf(255.5f + sm) + logf(255.5f + sp)) - 0.5f * (sm + sp);
}
__device__ inline void async16(const unsigned char* g, unsigned char* l) {
  __builtin_amdgcn_global_load_lds(
      (const __attribute__((address_space(1))) unsigned int*)g,
      (__attribute__((address_space(3))) unsigned int*)l, 16, 0, 0);
}
// pack 8 floats (scaled) -> 8 fp8 e4m3 bytes (2 dwords)
__device__ inline int2 pack_fp8x8(const float* v, float s) {
  int lo = 0, hi = 0;
  lo = __builtin_amdgcn_cvt_pk_fp8_f32(v[0] * s, v[1] * s, lo, false);
  lo = __builtin_amdgcn_cvt_pk_fp8_f32(v[2] * s, v[3] * s, lo, true);
  hi = __builtin_amdgcn_cvt_pk_fp8_f32(v[4] * s, v[5] * s, hi, false);
  hi = __builtin_amdgcn_cvt_pk_fp8_f32(v[6] * s, v[7] * s, hi, true);
  return make_int2(lo, hi);
}
// packed-row byte offset for lane l holding k in [8l, 8l+8):
// 64-byte K-block = (l>>3); slot = l&3; halves interleave per verified map.
__device__ inline int pk_off(int l) {
  return ((l >> 3) << 6) + ((l & 3) << 4) + (((l & 7) < 4) ? 0 : 8);
}

// ---------- fused prep (blocks 0..2047, one WAVE per class) + sample ----------
__global__ __launch_bounds__(256) void prep_sample(const float* __restrict__ weight,
                                                   const float* __restrict__ params,
                                                   const float* __restrict__ lscale,
                                                   unsigned char* __restrict__ muW8,
                                                   float4* __restrict__ cparams,
                                                   float* __restrict__ rowsum,
                                                   float4* __restrict__ out4,
                                                   unsigned char* __restrict__ Sb8) {
  int blk = blockIdx.x, tid = threadIdx.x;
  int wave = tid >> 6, lane = tid & 63;
  if (blk < 2048) {
    out4[(size_t)blk * 512 + tid]       = make_float4(0.f, 0.f, 0.f, 0.f);
    out4[(size_t)blk * 512 + 256 + tid] = make_float4(0.f, 0.f, 0.f, 0.f);
    if (blk < 20) rowsum[blk * 256 + tid] = 0.0f;   // 20*256 = 5120

    int c = blk * 4 + wave;                 // one wave per class
    const float* wr = weight + (size_t)c * (DIMD + 2) + 1;
    float v[8];
    float n2 = 0.0f;
    #pragma unroll
    for (int j = 0; j < 8; j++) { v[j] = wr[lane * 8 + j]; n2 += v[j] * v[j]; }
    n2 = wave_sum(n2);
    float inv = rsqrtf(n2) * 16.0f;         // x16: dodge e4m3 subnormals
    int2 pk = pack_fp8x8(v, inv);
    *(int2*)(muW8 + (size_t)c * 512 + pk_off(lane)) = pk;

    float hik = wr[DIMD];                   // col 513
    float kw = expf(-hik);
    float k1 = expf(lscale[0]);
    float lcw = vmf_logc(kw);
    float A2 = fmaf(k1, k1, kw * kw);
    float B2 = 2.0f * k1 * kw;
    const float X0 = 0.9238795f, X1 = 0.3826834f;
    int l3 = lane & 3;
    float Xj = (l3 == 0) ? X0 : (l3 == 1) ? X1 : (l3 == 2) ? -X1 : -X0;
    float gj = lcw - vmf_logc(sqrtf(fmaf(B2, Xj, A2)));
    float g0 = __shfl(gj, 0, 64), g1 = __shfl(gj, 1, 64);
    float g2 = __shfl(gj, 2, 64), g3 = __shfl(gj, 3, 64);
    if (lane == 0) {
      float b0 = 0.25f * (g0 + g1 + g2 + g3);
      float b1 = 0.5f * (X0 * (g0 - g3) + X1 * (g1 - g2));
      float b2 = 0.5f * 0.7071068f * ((g0 + g3) - (g1 + g2));
      float b3 = 0.5f * (X1 * (g0 - g3) - X0 * (g1 - g2));
      const float L2E = 1.4426950409f;
      const float S1 = 1.0f / 256.0f;       // acc = 256*cos -> rescale poly
      float c0f = (b0 - b2) * L2E;
      float c1f = (b1 - 3.0f * b3) * L2E * S1;
      float c2f = (2.0f * b2) * L2E * S1 * S1;
      float c3f = (4.0f * b3) * L2E * S1 * S1 * S1;
      cparams[c] = make_float4(c0f, c1f, c2f, c3f);
    }
  } else {
    // sample: 1 wave per row; lane l owns k in [8l, 8l+8) (contiguous).
    int row = (blk - 2048) * 4 + wave;      // b*KSAMP + k
    int b = row / KSAMP;
    const float* pr = params + (size_t)b * (DIMD + 2) + 1;

    float mu[8];
    float n2 = 0.0f;
    #pragma unroll
    for (int j = 0; j < 8; j++) { mu[j] = pr[lane * 8 + j]; n2 += mu[j] * mu[j]; }
    n2 = wave_sum(n2);
    float invn = rsqrtf(n2);
    #pragma unroll
    for (int j = 0; j < 8; j++) mu[j] *= invn;

    float kap = __expf(-pr[DIMD]);
    float bb = (-2.0f * kap + sqrtf(fmaf(4.0f * kap, kap, 511.0f * 511.0f))) / 511.0f;
    float x0 = (1.0f - bb) / (1.0f + bb);
    float cc = kap * x0 + 511.0f * __logf(1.0f - x0 * x0);

    uint64_t ctr = (((uint64_t)(row + 1)) << 32) | ((uint64_t)lane << 8);
    float g1 = gamma255(ctr);
    float g2 = gamma255(ctr);
    float z = g1 / (g1 + g2);
    float wt = (1.0f - (1.0f + bb) * z) / (1.0f - (1.0f - bb) * z);
    uint64_t r = sm64(ctr++);
    float u = u01((uint32_t)(r >> 32));
    float lhs = kap * wt + 511.0f * __logf(1.0f - x0 * wt) - cc;
    bool acc = (lane < TREJ) && (lhs >= __logf(fmaxf(u, 1e-10f)));
    uint64_t mask = __ballot(acc);
    int sel = mask ? (__ffsll((unsigned long long)mask) - 1) : 0;
    float w = __shfl(wt, sel, 64);

    uint64_t cbase = (((uint64_t)(row + 1)) << 32) | 0x40000000ull;
    float v[8];
    #pragma unroll
    for (int j = 0; j < 8; j++) v[j] = normal_from(sm64(cbase + (uint64_t)(lane * 8 + j)));
    float d = 0.0f;
    #pragma unroll
    for (int j = 0; j < 8; j++) d += v[j] * mu[j];
    d = wave_sum(d);
    float t2 = 0.0f;
    #pragma unroll
    for (int j = 0; j < 8; j++) { v[j] -= d * mu[j]; t2 += v[j] * v[j]; }
    t2 = wave_sum(t2);
    float ivt = rsqrtf(t2);
    float st = sqrtf(fmaxf(0.0f, 1.0f - w * w)) * ivt;
    float sv[8];
    float s2 = 0.0f;
    #pragma unroll
    for (int j = 0; j < 8; j++) { sv[j] = fmaf(st, v[j], w * mu[j]); s2 += sv[j] * sv[j]; }
    s2 = wave_sum(s2);
    float is = rsqrtf(s2) * 16.0f;          // x16 scale for fp8
    int2 pk = pack_fp8x8(sv, is);
    *(int2*)(Sb8 + (size_t)row * 512 + pk_off(lane)) = pk;
  }
}

// MFMA GEMM: fp8 e4m3, 256x128 tile, BK=64, 8 iterations (R8 skeleton).
// LDS row = 64 B = 4 x 16B slots, verified XOR swizzle (byte-identical
// geometry to the 0-conflict bf16 layout). Each b128 frag = two K=32 steps.
__global__ __launch_bounds__(256, 2) void gemm_lse(const unsigned char* __restrict__ Sb8,
                                                   const unsigned char* __restrict__ Wb8,
                                                   const float4* __restrict__ cparams,
                                                   float* __restrict__ rowsum) {
  __shared__ __align__(16) unsigned char As[2][256 * 64];   // 2 x 16 KB
  __shared__ __align__(16) unsigned char Bs[2][128 * 64];   // 2 x 8 KB
  int tid = threadIdx.x;
  int lane = tid & 63, wave = tid >> 6;
  int tx = lane & 15, tz = lane >> 4;

  int id = blockIdx.x;                       // 64 col-tiles x 20 row-tiles = 1280
  int xcd = id & 7, lid = id >> 3;           // 160 blocks per XCD
  int c0 = (xcd * 8 + (lid & 7)) * 128;      // 8-coltile stripe per XCD
  int r0 = (lid >> 3) * 256;                 // sweep 20 row tiles

  int srow = (lane >> 2);                       // 0..15 within chunk
  int kg   = (lane & 3) ^ ((lane >> 3) & 3);    // verified swizzle
  int chA0 = wave * 4;                          // A: 16 chunks of 16 rows
  int chB0 = wave * 2;                          // B: 8 chunks

  f32x4 acc[4][8];
  #pragma unroll
  for (int i = 0; i < 4; i++)
    #pragma unroll
    for (int j = 0; j < 8; j++) acc[i][j] = (f32x4){0.f, 0.f, 0.f, 0.f};

  #pragma unroll
  for (int c = 0; c < 4; c++) {
    int ch = chA0 + c, rowi = ch * 16 + srow;
    async16(&Sb8[(size_t)(r0 + rowi) * 512 + kg * 16], &As[0][ch * 1024]);
  }
  #pragma unroll
  for (int c = 0; c < 2; c++) {
    int ch = chB0 + c, rowi = ch * 16 + srow;
    async16(&Wb8[(size_t)(c0 + rowi) * 512 + kg * 16], &Bs[0][ch * 1024]);
  }

  int p = 0;
  for (int kt = 0; kt < 512; kt += 64) {       // 8 iterations
    __syncthreads();   // publishes buf[p]
    if (kt + 64 < 512) {
      #pragma unroll
      for (int c = 0; c < 4; c++) {
        int ch = chA0 + c, rowi = ch * 16 + srow;
        async16(&Sb8[(size_t)(r0 + rowi) * 512 + kt + 64 + kg * 16], &As[p ^ 1][ch * 1024]);
      }
      #pragma unroll
      for (int c = 0; c < 2; c++) {
        int ch = chB0 + c, rowi = ch * 16 + srow;
        async16(&Wb8[(size_t)(c0 + rowi) * 512 + kt + 64 + kg * 16], &Bs[p ^ 1][ch * 1024]);
      }
    }
    l2 af[4], bf[8];
    int sA = tz ^ ((tx >> 1) & 3);
    #pragma unroll
    for (int mi = 0; mi < 4; mi++)
      af[mi] = *(const l2*)&As[p][(wave * 64 + mi * 16 + tx) * 64 + sA * 16];
    #pragma unroll
    for (int ni = 0; ni < 8; ni++)
      bf[ni] = *(const l2*)&Bs[p][(ni * 16 + tx) * 64 + sA * 16];
    #pragma unroll
    for (int mi = 0; mi < 4; mi++)
      #pragma unroll
      for (int ni = 0; ni < 8; ni++) {
        acc[mi][ni] = __builtin_amdgcn_mfma_f32_16x16x32_fp8_fp8(af[mi].x, bf[ni].x, acc[mi][ni], 0, 0, 0);
        acc[mi][ni] = __builtin_amdgcn_mfma_f32_16x16x32_fp8_fp8(af[mi].y, bf[ni].y, acc[mi][ni], 0, 0, 0);
      }
    p ^= 1;
  }

  // epilogue: s += 2^(cubic(acc)) per class (poly pre-scaled for acc=256*cos)
  float4 cp[8];
  #pragma unroll
  for (int ni = 0; ni < 8; ni++) cp[ni] = cparams[c0 + ni * 16 + tx];

  #pragma unroll
  for (int mi = 0; mi < 4; mi++) {
    #pragma unroll
    for (int reg = 0; reg < 4; reg++) {
      float s = 0.0f;
      #pragma unroll
      for (int ni = 0; ni < 8; ni++) {
        float cv = acc[mi][ni][reg];
        float g = fmaf(fmaf(fmaf(cp[ni].w, cv, cp[ni].z), cv, cp[ni].y), cv, cp[ni].x);
        s += exp2f(g);
      }
      #pragma unroll
      for (int o = 1; o < 16; o <<= 1) s += __shfl_xor(s, o, 64);
      if (tx == 0)
        atomicAdd(&rowsum[r0 + wave * 64 + mi * 16 + tz * 4 + reg], s);
    }
  }
}

// finalize: recompute both unit vectors from raw fp32 inputs (label term
// stays fp32-exact; no dependency on the packed fp8 layout).
__global__ __launch_bounds__(64) void finalize_kernel(const float* __restrict__ params,
                                                      const float* __restrict__ weight,
                                                      const float* __restrict__ rowsum,
                                                      const int* __restrict__ labels,
                                                      const float* __restrict__ lscale,
                                                      float* __restrict__ out) {
  int b = blockIdx.x;
  int lane = threadIdx.x;
  int lab = labels[b];
  const float* pr = params + (size_t)b * (DIMD + 2) + 1;
  const float* wr = weight + (size_t)lab * (DIMD + 2) + 1;
  float nx = 0.0f, nw = 0.0f, d = 0.0f;
  #pragma unroll
  for (int j = 0; j < 8; j++) {
    float xv = pr[j * 64 + lane];
    float wv = wr[j * 64 + lane];
    nx += xv * xv; nw += wv * wv; d += xv * wv;
  }
  nx = wave_sum(nx); nw = wave_sum(nw); d = wave_sum(d);
  if (lane == 0) {
    float k1 = expf(lscale[0]);
    float acc = 0.0f;
    #pragma unroll
    for (int k = 0; k < KSAMP; k++) acc += __logf(rowsum[b * KSAMP + k]);
    float loss = acc * (1.0f / KSAMP) - k1 * d * rsqrtf(nx) * rsqrtf(nw);
    out[(size_t)b * NCLS + lab] = -loss;
  }
}

// ---------------- launch ----------------
extern "C" void kernel_launch(void* const* d_in, const int* in_sizes, int n_in,
                              void* d_out, int out_size, void* d_ws, size_t ws_size,
                              hipStream_t stream) {
  const float* params = (const float*)d_in[0];
  const float* weight = (const float*)d_in[1];
  const float* lscale = (const float*)d_in[2];
  const int*   labels = (const int*)d_in[3];
  float* out = (float*)d_out;
  char* ws = (char*)d_ws;

  unsigned char* muW8    = (unsigned char*)(ws);                    // 8192*512 = 4,194,304
  unsigned char* Sb8     = (unsigned char*)(ws + 4194304);          // 5120*512 = 2,621,440
  float4*        cparams = (float4*)(ws + 6815744);                 // 8192*16  =   131,072
  float*         rowsum  = (float*)(ws + 6946816);                  // 5120*4   =    20,480

  hipLaunchKernelGGL(prep_sample, dim3(2048 + BATCH * KSAMP / 4), dim3(256), 0, stream,
                     weight, params, lscale, muW8, cparams, rowsum, (float4*)out, Sb8);
  hipLaunchKernelGGL(gemm_lse, dim3((NCLS / 128) * (BATCH * KSAMP / 256)), dim3(256), 0, stream,
                     Sb8, muW8, cparams, rowsum);
  hipLaunchKernelGGL(finalize_kernel, dim3(BATCH), dim3(64), 0, stream,
                     params, weight, rowsum, labels, lscale, out);
}

// Round 12
// 140.551 us; speedup vs baseline: 1.4766x; 1.0034x over previous
//
#include <hip/hip_runtime.h>
#include <stdint.h>

#define DIMD 512
#define BATCH 512
#define KSAMP 10
#define NCLS 8192
#define TREJ 32

typedef float f32x4 __attribute__((ext_vector_type(4)));
typedef long l2 __attribute__((ext_vector_type(2)));

// ---------------- RNG (counter-based, deterministic) ----------------
__device__ inline uint64_t sm64(uint64_t x) {
  x += 0x9E3779B97F4A7C15ull;
  x = (x ^ (x >> 30)) * 0xBF58476D1CE4E5B9ull;
  x = (x ^ (x >> 27)) * 0x94D049BB133111EBull;
  return x ^ (x >> 31);
}
__device__ inline float u01(uint32_t u) {
  return ((float)u + 0.5f) * 2.3283064365386963e-10f;
}
__device__ inline float normal_from(uint64_t r) {
  float u1 = u01((uint32_t)(r >> 32));
  float u2 = u01((uint32_t)r);
  return sqrtf(-2.0f * __logf(u1)) * __cosf(6.28318530718f * u2);
}
__device__ inline float gamma255(uint64_t& ctr) {
  const float dg = 255.1666667f;
  const float cg = 0.02086730f;
  for (int i = 0; i < 16; i++) {
    uint64_t r = sm64(ctr++);
    float x = normal_from(r);
    float t = fmaf(cg, x, 1.0f);
    if (t <= 0.0f) continue;
    float v3 = t * t * t;
    uint64_t r2 = sm64(ctr++);
    float u3 = u01((uint32_t)(r2 >> 32));
    if (__logf(u3) < 0.5f * x * x + dg * (1.0f - v3 + __logf(v3))) return dg * v3;
  }
  return dg;
}
__device__ inline float wave_sum(float v) {
  #pragma unroll
  for (int o = 32; o > 0; o >>= 1) v += __shfl_down(v, o, 64);
  return __shfl(v, 0, 64);
}
__device__ inline float vmf_logc(float k) {
  float k2 = k * k;
  float sm = sqrtf(65280.25f + k2);
  float sp = sqrtf(65792.25f + k2);
  return 127.75f * (logf(255.5f + sm) + logf(255.5f + sp)) - 0.5f * (sm + sp);
}
// pack 8 floats (scaled) -> 8 fp8 e4m3 bytes (2 dwords)
__device__ inline int2 pack_fp8x8(const float* v, float s) {
  int lo = 0, hi = 0;
  lo = __builtin_amdgcn_cvt_pk_fp8_f32(v[0] * s, v[1] * s, lo, false);
  lo = __builtin_amdgcn_cvt_pk_fp8_f32(v[2] * s, v[3] * s, lo, true);
  hi = __builtin_amdgcn_cvt_pk_fp8_f32(v[4] * s, v[5] * s, hi, false);
  hi = __builtin_amdgcn_cvt_pk_fp8_f32(v[6] * s, v[7] * s, hi, true);
  return make_int2(lo, hi);
}
// packed-row byte offset for lane l holding k in [8l, 8l+8) (verified map)
__device__ inline int pk_off(int l) {
  return ((l >> 3) << 6) + ((l & 3) << 4) + (((l & 7) < 4) ? 0 : 8);
}
// lgkm-only barrier: buffer_loads (wave-private VGPR dests) stay in flight.
__device__ inline void sync_lds() {
  asm volatile("s_waitcnt lgkmcnt(0)\n\ts_barrier" ::: "memory");
}

// ---------- fused prep (blocks 0..2047, one WAVE per class) + sample ----------
__global__ __launch_bounds__(256) void prep_sample(const float* __restrict__ weight,
                                                   const float* __restrict__ params,
                                                   const float* __restrict__ lscale,
                                                   unsigned char* __restrict__ muW8,
                                                   float4* __restrict__ cparams,
                                                   float* __restrict__ rowsum,
                                                   float4* __restrict__ out4,
                                                   unsigned char* __restrict__ Sb8) {
  int blk = blockIdx.x, tid = threadIdx.x;
  int wave = tid >> 6, lane = tid & 63;
  if (blk < 2048) {
    out4[(size_t)blk * 512 + tid]       = make_float4(0.f, 0.f, 0.f, 0.f);
    out4[(size_t)blk * 512 + 256 + tid] = make_float4(0.f, 0.f, 0.f, 0.f);
    if (blk < 20) rowsum[blk * 256 + tid] = 0.0f;   // 20*256 = 5120

    int c = blk * 4 + wave;                 // one wave per class
    const float* wr = weight + (size_t)c * (DIMD + 2) + 1;
    float v[8];
    float n2 = 0.0f;
    #pragma unroll
    for (int j = 0; j < 8; j++) { v[j] = wr[lane * 8 + j]; n2 += v[j] * v[j]; }
    n2 = wave_sum(n2);
    float inv = rsqrtf(n2) * 16.0f;         // x16: dodge e4m3 subnormals
    int2 pk = pack_fp8x8(v, inv);
    *(int2*)(muW8 + (size_t)c * 512 + pk_off(lane)) = pk;

    float hik = wr[DIMD];                   // col 513
    float kw = expf(-hik);
    float k1 = expf(lscale[0]);
    float lcw = vmf_logc(kw);
    float A2 = fmaf(k1, k1, kw * kw);
    float B2 = 2.0f * k1 * kw;
    const float X0 = 0.9238795f, X1 = 0.3826834f;
    int l3 = lane & 3;
    float Xj = (l3 == 0) ? X0 : (l3 == 1) ? X1 : (l3 == 2) ? -X1 : -X0;
    float gj = lcw - vmf_logc(sqrtf(fmaf(B2, Xj, A2)));
    float g0 = __shfl(gj, 0, 64), g1 = __shfl(gj, 1, 64);
    float g2 = __shfl(gj, 2, 64), g3 = __shfl(gj, 3, 64);
    if (lane == 0) {
      float b0 = 0.25f * (g0 + g1 + g2 + g3);
      float b1 = 0.5f * (X0 * (g0 - g3) + X1 * (g1 - g2));
      float b2 = 0.5f * 0.7071068f * ((g0 + g3) - (g1 + g2));
      float b3 = 0.5f * (X1 * (g0 - g3) - X0 * (g1 - g2));
      const float L2E = 1.4426950409f;
      const float S1 = 1.0f / 256.0f;       // acc = 256*cos -> rescale poly
      cparams[c] = make_float4((b0 - b2) * L2E, (b1 - 3.0f * b3) * L2E * S1,
                               (2.0f * b2) * L2E * S1 * S1,
                               (4.0f * b3) * L2E * S1 * S1 * S1);
    }
  } else {
    // sample: 1 wave per row; lane l owns k in [8l, 8l+8) (contiguous).
    int row = (blk - 2048) * 4 + wave;      // b*KSAMP + k
    int b = row / KSAMP;
    const float* pr = params + (size_t)b * (DIMD + 2) + 1;

    float mu[8];
    float n2 = 0.0f;
    #pragma unroll
    for (int j = 0; j < 8; j++) { mu[j] = pr[lane * 8 + j]; n2 += mu[j] * mu[j]; }
    n2 = wave_sum(n2);
    float invn = rsqrtf(n2);
    #pragma unroll
    for (int j = 0; j < 8; j++) mu[j] *= invn;

    float kap = __expf(-pr[DIMD]);
    float bb = (-2.0f * kap + sqrtf(fmaf(4.0f * kap, kap, 511.0f * 511.0f))) / 511.0f;
    float x0 = (1.0f - bb) / (1.0f + bb);
    float cc = kap * x0 + 511.0f * __logf(1.0f - x0 * x0);

    uint64_t ctr = (((uint64_t)(row + 1)) << 32) | ((uint64_t)lane << 8);
    float g1 = gamma255(ctr);
    float g2 = gamma255(ctr);
    float z = g1 / (g1 + g2);
    float wt = (1.0f - (1.0f + bb) * z) / (1.0f - (1.0f - bb) * z);
    uint64_t r = sm64(ctr++);
    float u = u01((uint32_t)(r >> 32));
    float lhs = kap * wt + 511.0f * __logf(1.0f - x0 * wt) - cc;
    bool acc = (lane < TREJ) && (lhs >= __logf(fmaxf(u, 1e-10f)));
    uint64_t mask = __ballot(acc);
    int sel = mask ? (__ffsll((unsigned long long)mask) - 1) : 0;
    float w = __shfl(wt, sel, 64);

    uint64_t cbase = (((uint64_t)(row + 1)) << 32) | 0x40000000ull;
    float v[8];
    #pragma unroll
    for (int j = 0; j < 8; j++) v[j] = normal_from(sm64(cbase + (uint64_t)(lane * 8 + j)));
    float d = 0.0f;
    #pragma unroll
    for (int j = 0; j < 8; j++) d += v[j] * mu[j];
    d = wave_sum(d);
    float t2 = 0.0f;
    #pragma unroll
    for (int j = 0; j < 8; j++) { v[j] -= d * mu[j]; t2 += v[j] * v[j]; }
    t2 = wave_sum(t2);
    float ivt = rsqrtf(t2);
    float st = sqrtf(fmaxf(0.0f, 1.0f - w * w)) * ivt;
    float sv[8];
    float s2 = 0.0f;
    #pragma unroll
    for (int j = 0; j < 8; j++) { sv[j] = fmaf(st, v[j], w * mu[j]); s2 += sv[j] * sv[j]; }
    s2 = wave_sum(s2);
    float is = rsqrtf(s2) * 16.0f;
    int2 pk = pack_fp8x8(sv, is);
    *(int2*)(Sb8 + (size_t)row * 512 + pk_off(lane)) = pk;
  }
}

// MFMA GEMM: fp8 e4m3, 256x128 tile, BK=64, 8 iterations.
// AITER-style register pipeline: buffer_load -> named VGPR sets (static
// indices, fully unrolled) -> ds_write (linear base+lane*16, identical to the
// verified async16 address pattern = 0 conflicts) -> lgkm-only barrier, so
// buffer_loads stay in flight ACROSS barriers (vmcnt never forced to 0).
// MFMA order: all .x then all .y per B-half (no dependent adjacent pairs).
__global__ __launch_bounds__(256, 2) void gemm_lse(const unsigned char* __restrict__ Sb8,
                                                   const unsigned char* __restrict__ Wb8,
                                                   const float4* __restrict__ cparams,
                                                   float* __restrict__ rowsum) {
  __shared__ __align__(16) unsigned char As[2][256 * 64];   // 2 x 16 KB
  __shared__ __align__(16) unsigned char Bs[2][128 * 64];   // 2 x 8 KB
  int tid = threadIdx.x;
  int lane = tid & 63, wave = tid >> 6;
  int tx = lane & 15, tz = lane >> 4;

  int id = blockIdx.x;                       // 64 col-tiles x 20 row-tiles = 1280
  int xcd = id & 7, lid = id >> 3;           // 160 blocks per XCD
  int c0 = (xcd * 8 + (lid & 7)) * 128;      // 8-coltile stripe per XCD
  int r0 = (lid >> 3) * 256;                 // sweep 20 row tiles

  int srow = lane >> 2;                      // 0..15 within chunk
  int slot = lane & 3;
  int kg = slot ^ ((srow >> 1) & 3);         // verified swizzle
  // global pointers: A chunks wave*4..+3 (16 rows each), B chunks wave*2..+1
  const unsigned char* gA[4];
  const unsigned char* gB[2];
  #pragma unroll
  for (int c = 0; c < 4; c++)
    gA[c] = Sb8 + (size_t)(r0 + (wave * 4 + c) * 16 + srow) * 512 + kg * 16;
  #pragma unroll
  for (int c = 0; c < 2; c++)
    gB[c] = Wb8 + (size_t)(c0 + (wave * 2 + c) * 16 + srow) * 512 + kg * 16;
  int ldsAo = (wave * 4) * 1024 + lane * 16;   // + c*1024
  int ldsBo = (wave * 2) * 1024 + lane * 16;

  f32x4 acc[4][8];
  #pragma unroll
  for (int i = 0; i < 4; i++)
    #pragma unroll
    for (int j = 0; j < 8; j++) acc[i][j] = (f32x4){0.f, 0.f, 0.f, 0.f};

  int4 ar0[4], br0[2];   // set 0: even chunks
  int4 ar1[4], br1[2];   // set 1: odd chunks

#define LOADCH(CI, AR, BR)                                   \
  { AR[0] = *(const int4*)(gA[0] + (CI) * 64);               \
    AR[1] = *(const int4*)(gA[1] + (CI) * 64);               \
    AR[2] = *(const int4*)(gA[2] + (CI) * 64);               \
    AR[3] = *(const int4*)(gA[3] + (CI) * 64);               \
    BR[0] = *(const int4*)(gB[0] + (CI) * 64);               \
    BR[1] = *(const int4*)(gB[1] + (CI) * 64); }

#define WRITELDS(P, AR, BR)                                  \
  { *(int4*)&As[P][ldsAo]        = AR[0];                    \
    *(int4*)&As[P][ldsAo + 1024] = AR[1];                    \
    *(int4*)&As[P][ldsAo + 2048] = AR[2];                    \
    *(int4*)&As[P][ldsAo + 3072] = AR[3];                    \
    *(int4*)&Bs[P][ldsBo]        = BR[0];                    \
    *(int4*)&Bs[P][ldsBo + 1024] = BR[1]; }

#define COMPUTE(P)                                                        \
  { l2 af[4];                                                             \
    int sA_ = tz ^ ((tx >> 1) & 3);                                       \
    _Pragma("unroll")                                                     \
    for (int mi = 0; mi < 4; mi++)                                        \
      af[mi] = *(const l2*)&As[P][(wave * 64 + mi * 16 + tx) * 64 + sA_ * 16]; \
    _Pragma("unroll")                                                     \
    for (int h = 0; h < 2; h++) {                                         \
      l2 bf[4];                                                           \
      _Pragma("unroll")                                                   \
      for (int ni = 0; ni < 4; ni++)                                      \
        bf[ni] = *(const l2*)&Bs[P][((h * 4 + ni) * 16 + tx) * 64 + sA_ * 16]; \
      _Pragma("unroll")                                                   \
      for (int mi = 0; mi < 4; mi++)                                      \
        _Pragma("unroll")                                                 \
        for (int ni = 0; ni < 4; ni++)                                    \
          acc[mi][h * 4 + ni] = __builtin_amdgcn_mfma_f32_16x16x32_fp8_fp8(af[mi].x, bf[ni].x, acc[mi][h * 4 + ni], 0, 0, 0); \
      _Pragma("unroll")                                                   \
      for (int mi = 0; mi < 4; mi++)                                      \
        _Pragma("unroll")                                                 \
        for (int ni = 0; ni < 4; ni++)                                    \
          acc[mi][h * 4 + ni] = __builtin_amdgcn_mfma_f32_16x16x32_fp8_fp8(af[mi].y, bf[ni].y, acc[mi][h * 4 + ni], 0, 0, 0); \
    } }

  // prologue: chunks 0,1 in flight; publish chunk 0
  LOADCH(0, ar0, br0);
  LOADCH(1, ar1, br1);
  WRITELDS(0, ar0, br0);
  sync_lds();

#define GITER_EVEN(IT)                                       \
  { if ((IT) + 2 < 8) LOADCH((IT) + 2, ar0, br0);            \
    COMPUTE(0);                                              \
    if ((IT) + 1 < 8) WRITELDS(1, ar1, br1);                 \
    if ((IT) < 7) sync_lds(); }

#define GITER_ODD(IT)                                        \
  { if ((IT) + 2 < 8) LOADCH((IT) + 2, ar1, br1);            \
    COMPUTE(1);                                              \
    if ((IT) + 1 < 8) WRITELDS(0, ar0, br0);                 \
    if ((IT) < 7) sync_lds(); }

  GITER_EVEN(0) GITER_ODD(1) GITER_EVEN(2) GITER_ODD(3)
  GITER_EVEN(4) GITER_ODD(5) GITER_EVEN(6) GITER_ODD(7)

  // epilogue: s += 2^(cubic(acc)) per class (poly pre-scaled for acc=256*cos)
  float4 cp[8];
  #pragma unroll
  for (int ni = 0; ni < 8; ni++) cp[ni] = cparams[c0 + ni * 16 + tx];

  #pragma unroll
  for (int mi = 0; mi < 4; mi++) {
    #pragma unroll
    for (int reg = 0; reg < 4; reg++) {
      float s = 0.0f;
      #pragma unroll
      for (int ni = 0; ni < 8; ni++) {
        float cv = acc[mi][ni][reg];
        float g = fmaf(fmaf(fmaf(cp[ni].w, cv, cp[ni].z), cv, cp[ni].y), cv, cp[ni].x);
        s += exp2f(g);
      }
      #pragma unroll
      for (int o = 1; o < 16; o <<= 1) s += __shfl_xor(s, o, 64);
      if (tx == 0)
        atomicAdd(&rowsum[r0 + wave * 64 + mi * 16 + tz * 4 + reg], s);
    }
  }
}

// finalize: recompute both unit vectors from raw fp32 inputs
__global__ __launch_bounds__(64) void finalize_kernel(const float* __restrict__ params,
                                                      const float* __restrict__ weight,
                                                      const float* __restrict__ rowsum,
                                                      const int* __restrict__ labels,
                                                      const float* __restrict__ lscale,
                                                      float* __restrict__ out) {
  int b = blockIdx.x;
  int lane = threadIdx.x;
  int lab = labels[b];
  const float* pr = params + (size_t)b * (DIMD + 2) + 1;
  const float* wr = weight + (size_t)lab * (DIMD + 2) + 1;
  float nx = 0.0f, nw = 0.0f, d = 0.0f;
  #pragma unroll
  for (int j = 0; j < 8; j++) {
    float xv = pr[j * 64 + lane];
    float wv = wr[j * 64 + lane];
    nx += xv * xv; nw += wv * wv; d += xv * wv;
  }
  nx = wave_sum(nx); nw = wave_sum(nw); d = wave_sum(d);
  if (lane == 0) {
    float k1 = expf(lscale[0]);
    float acc = 0.0f;
    #pragma unroll
    for (int k = 0; k < KSAMP; k++) acc += __logf(rowsum[b * KSAMP + k]);
    float loss = acc * (1.0f / KSAMP) - k1 * d * rsqrtf(nx) * rsqrtf(nw);
    out[(size_t)b * NCLS + lab] = -loss;
  }
}

// ---------------- launch ----------------
extern "C" void kernel_launch(void* const* d_in, const int* in_sizes, int n_in,
                              void* d_out, int out_size, void* d_ws, size_t ws_size,
                              hipStream_t stream) {
  const float* params = (const float*)d_in[0];
  const float* weight = (const float*)d_in[1];
  const float* lscale = (const float*)d_in[2];
  const int*   labels = (const int*)d_in[3];
  float* out = (float*)d_out;
  char* ws = (char*)d_ws;

  unsigned char* muW8    = (unsigned char*)(ws);                    // 8192*512 = 4,194,304
  unsigned char* Sb8     = (unsigned char*)(ws + 4194304);          // 5120*512 = 2,621,440
  float4*        cparams = (float4*)(ws + 6815744);                 // 8192*16  =   131,072
  float*         rowsum  = (float*)(ws + 6946816);                  // 5120*4   =    20,480

  hipLaunchKernelGGL(prep_sample, dim3(2048 + BATCH * KSAMP / 4), dim3(256), 0, stream,
                     weight, params, lscale, muW8, cparams, rowsum, (float4*)out, Sb8);
  hipLaunchKernelGGL(gemm_lse, dim3((NCLS / 128) * (BATCH * KSAMP / 256)), dim3(256), 0, stream,
                     Sb8, muW8, cparams, rowsum);
  hipLaunchKernelGGL(finalize_kernel, dim3(BATCH), dim3(64), 0, stream,
                     params, weight, rowsum, labels, lscale, out);
}